// Round 10
// baseline (12383.069 us; speedup 1.0000x reference)
//
#include <hip/hip_runtime.h>

#define NB 128
#define NT 512
#define NE 256
#define NH 512
#define NA 64
#define NG 8      // groups (one per XCD via blockIdx%8)
#define WPG 32    // workgroups per group
#define GB 16     // batches per group

typedef short bf16x8 __attribute__((ext_vector_type(8)));
typedef float f32x4 __attribute__((ext_vector_type(4)));
typedef unsigned short u16x8 __attribute__((ext_vector_type(8)));
typedef unsigned long long u64;
typedef unsigned short us;

__device__ __forceinline__ us f2bf(float f){
  unsigned u = __builtin_bit_cast(unsigned, f);
  u = u + 0x7fffu + ((u >> 16) & 1u);
  return (us)(u >> 16);
}
__device__ __forceinline__ float bf2f(us h){
  unsigned u = ((unsigned)h) << 16;
  return __builtin_bit_cast(float, u);
}
__device__ __forceinline__ bf16x8 packbf2(f32x4 a, f32x4 b){
  bf16x8 r;
  r[0]=(short)f2bf(a[0]); r[1]=(short)f2bf(a[1]); r[2]=(short)f2bf(a[2]); r[3]=(short)f2bf(a[3]);
  r[4]=(short)f2bf(b[0]); r[5]=(short)f2bf(b[1]); r[6]=(short)f2bf(b[2]); r[7]=(short)f2bf(b[3]);
  return r;
}
__device__ __forceinline__ bf16x8 loadB_f32(const float* p){
  f32x4 a = *(const f32x4*)p;
  f32x4 b = *(const f32x4*)(p + 4);
  return packbf2(a, b);
}
#define MFMA(a,b,c) __builtin_amdgcn_mfma_f32_16x16x32_bf16(a,b,c,0,0,0)
#define WAIT_VM0() __builtin_amdgcn_s_waitcnt(0x0F70)   // vmcnt(0) only

__device__ __forceinline__ float fsig(float x){
  return __builtin_amdgcn_rcpf(1.f + __expf(-x));
}
__device__ __forceinline__ float ftanh(float x){
  float e2 = __expf(2.f * x);
  return 1.f - 2.f * __builtin_amdgcn_rcpf(e2 + 1.f);
}

// ---- coherent LLC helpers (R8-proven commit-on-retire protocol) ----
struct fpair { float x, y; };
__device__ __forceinline__ fpair aload_f2(const float* p){
  u64 u = __hip_atomic_load((const u64*)p, __ATOMIC_RELAXED, __HIP_MEMORY_SCOPE_AGENT);
  fpair r;
  r.x = __builtin_bit_cast(float, (unsigned)u);
  r.y = __builtin_bit_cast(float, (unsigned)(u >> 32));
  return r;
}
__device__ __forceinline__ float aload_f(const float* p){
  return __hip_atomic_load(p, __ATOMIC_RELAXED, __HIP_MEMORY_SCOPE_AGENT);
}
__device__ __forceinline__ int aload_i(const int* p){
  return __hip_atomic_load(p, __ATOMIC_RELAXED, __HIP_MEMORY_SCOPE_AGENT);
}
__device__ __forceinline__ u64 astore_bf4r(us* p, f32x4 x){
  union { us s[4]; u64 u; } t;
  t.s[0]=f2bf(x[0]); t.s[1]=f2bf(x[1]); t.s[2]=f2bf(x[2]); t.s[3]=f2bf(x[3]);
  return __hip_atomic_exchange((u64*)p, t.u, __ATOMIC_RELAXED, __HIP_MEMORY_SCOPE_AGENT);
}
__device__ __forceinline__ u64 azero8r(u64* p){
  return __hip_atomic_exchange(p, 0ull, __ATOMIC_RELAXED, __HIP_MEMORY_SCOPE_AGENT);
}
__device__ __forceinline__ float afaddr(float* p, float v){
  return __hip_atomic_fetch_add(p, v, __ATOMIC_RELAXED, __HIP_MEMORY_SCOPE_AGENT);
}
__device__ __forceinline__ void arrive(int* c){
  if ((threadIdx.x & 63) == 0)
    (void)__hip_atomic_fetch_add(c, 1, __ATOMIC_RELAXED, __HIP_MEMORY_SCOPE_AGENT);
}
__device__ __forceinline__ void pollge(int* c, int tgt){
  while (aload_i(c) < tgt) __builtin_amdgcn_s_sleep(1);
}

// ---------------------------------------------------------------------------
// Pre-pass: tp[pos][a] = (embedding[token] . Wt[a,:]) + bt[a], stored bf16.
// ---------------------------------------------------------------------------
__global__ __launch_bounds__(256) void k_tp(
    const int* __restrict__ tok, const float* __restrict__ emb,
    const float* __restrict__ Wt, const float* __restrict__ bt,
    us* __restrict__ tp)
{
  const int lane = threadIdx.x & 63;
  const int w = threadIdx.x >> 6;
  const int m16 = lane & 15, quad = lane >> 4;

  bf16x8 wfq[8][4];
#pragma unroll
  for (int kc = 0; kc < 8; kc++)
#pragma unroll
    for (int nt = 0; nt < 4; nt++)
      wfq[kc][nt] = loadB_f32(Wt + (nt*16 + m16)*NE + kc*32 + quad*8);

  float btv[4];
#pragma unroll
  for (int nt = 0; nt < 4; nt++) btv[nt] = bt[nt*16 + m16];

  const int gw = blockIdx.x * 4 + w;
#pragma unroll 1
  for (int it = 0; it < 4; it++){
    const int pt = gw * 4 + it;
    const int pos = pt*16 + m16;
    const long row = (long)tok[pos];
    const float* xrow = emb + row * NE;
    f32x4 acc[4] = {{0,0,0,0},{0,0,0,0},{0,0,0,0},{0,0,0,0}};
#pragma unroll
    for (int kc = 0; kc < 8; kc++){
      bf16x8 af = loadB_f32(xrow + kc*32 + quad*8);
#pragma unroll
      for (int nt = 0; nt < 4; nt++)
        acc[nt] = MFMA(af, wfq[kc][nt], acc[nt]);
    }
#pragma unroll
    for (int nt = 0; nt < 4; nt++)
#pragma unroll
      for (int r = 0; r < 4; r++){
        int posr = pt*16 + quad*4 + r;
        tp[(long)posr * NA + nt*16 + m16] = f2bf(acc[nt][r] + btv[nt]);
      }
  }
}

// ---------------------------------------------------------------------------
// Pre-pass 2: pack Wq into bf16 MFMA A-fragment blob.
// ---------------------------------------------------------------------------
__global__ __launch_bounds__(256) void k_pack(
    const float* __restrict__ Wq, us* __restrict__ blob)
{
  const int lane = threadIdx.x & 63, wv = threadIdx.x >> 6;
  const int m16 = lane & 15, quad = lane >> 4;
#pragma unroll
  for (int kc = 0; kc < 16; kc++){
    bf16x8 t = loadB_f32(Wq + (long)(wv*16 + m16)*NH + kc*32 + quad*8);
    *(bf16x8*)&blob[((wv*16 + kc)*64 + lane)*8] = t;
  }
}

// ---------------------------------------------------------------------------
struct KArgs {
  const int* len;
  const float* bq; const float* v; const float* bv;
  const float* Wih0; const float* Whh0; const float* bih0; const float* bhh0;
  const float* Wih1; const float* Whh1; const float* bih1; const float* bhh1;
  const us* tp;
  const us* wqblob;
  us* h0b; us* h1b;
  float* ctxg;   // [2][GB][NA] per group (step-parity double buffer)
  float* deng;   // [2][GB] per group
  int* ctrl;
  float* out;
};

// Cooperative h staging: 256 threads pull 16KB into fragment-ordered LDS.
__device__ __forceinline__ void stage_h(const us* hb, us (*hs)[64][8], int tid){
  const int lane = tid & 63, wv = tid >> 6;
  const int b = lane & 15, quad = lane >> 4;
#pragma unroll
  for (int c = 0; c < 4; c++){
    const int kc = wv*4 + c;
    const us* src = hb + b*NH + kc*32 + quad*8;
    union { u64 u[2]; bf16x8 v; } t;
    t.u[0] = __hip_atomic_load((const u64*)src,     __ATOMIC_RELAXED, __HIP_MEMORY_SCOPE_AGENT);
    t.u[1] = __hip_atomic_load((const u64*)(src+4), __ATOMIC_RELAXED, __HIP_MEMORY_SCOPE_AGENT);
    *(bf16x8*)&hs[kc][lane][0] = t.v;
  }
}

// Wave roles per block:
//  w0: layer-0 owner of dims [16m,16m+16) -- all 3 gates, combine, h0 publish.
//  w1: layer-1 owner of dims [16m,16m+16) -- all 3 gates, combine, h1 publish.
//  w2/w3: q producers (2 slices each) + attention (64 slots per group).
__global__ __launch_bounds__(256, 1) void k_main(KArgs A_)
{
  const int tid = threadIdx.x, lane = tid & 63, w = tid >> 6;
  const int g = blockIdx.x & 7, m = blockIdx.x >> 3;
  const int m16 = lane & 15, quad = lane >> 4;
  const int d0 = m * 16;

  __shared__ __attribute__((aligned(16))) us h1s[16][64][8];    // 16KB
  __shared__ __attribute__((aligned(16))) us h0s[16][64][8];    // 16KB
  __shared__ __attribute__((aligned(16))) us wih1s[48][64][8];  // 48KB
  __shared__ __attribute__((aligned(16))) float qs[16][68];     // 4.25KB

  us* h0b = A_.h0b + g * GB * NH;
  us* h1b = A_.h1b + g * GB * NH;
  float* ctxg = A_.ctxg + g * 2 * GB * NA;
  float* deng = A_.deng + g * 2 * GB;
  int* c2 = A_.ctrl + g * 64;       // attention done (64/step)
  int* c3 = c2 + 16;                // h0 published   (32/step)
  int* c4 = c2 + 32;                // h1 published   (32/step, +64 init)
  const int b0 = g * GB;

  u64 usink = 0; float fsink = 0.f;

  // ----- persistent weights -----
  bf16x8 whhf[3][16];   // w0: Whh0 slice; w1: Whh1 slice
  bf16x8 wih0f[3][2];   // w0 only
  float bh[3][4], bi[3][4];
  if (w == 0){
#pragma unroll
    for (int gate = 0; gate < 3; gate++){
#pragma unroll
      for (int kc = 0; kc < 16; kc++)
        whhf[gate][kc] = loadB_f32(A_.Whh0 + (long)(gate*NH + d0 + m16)*NH + kc*32 + quad*8);
#pragma unroll
      for (int kc = 0; kc < 2; kc++)
        wih0f[gate][kc] = loadB_f32(A_.Wih0 + (gate*NH + d0 + m16)*NA + kc*32 + quad*8);
#pragma unroll
      for (int r = 0; r < 4; r++){
        bh[gate][r] = A_.bhh0[gate*NH + d0 + quad*4 + r];
        bi[gate][r] = A_.bih0[gate*NH + d0 + quad*4 + r];
      }
    }
  } else if (w == 1){
#pragma unroll
    for (int gate = 0; gate < 3; gate++){
#pragma unroll
      for (int kc = 0; kc < 16; kc++){
        whhf[gate][kc] = loadB_f32(A_.Whh1 + (long)(gate*NH + d0 + m16)*NH + kc*32 + quad*8);
        *(bf16x8*)&wih1s[gate*16 + kc][lane][0] =
            loadB_f32(A_.Wih1 + (long)(gate*NH + d0 + m16)*NH + kc*32 + quad*8);
      }
#pragma unroll
      for (int r = 0; r < 4; r++){
        bh[gate][r] = A_.bhh1[gate*NH + d0 + quad*4 + r];
        bi[gate][r] = A_.bih1[gate*NH + d0 + quad*4 + r];
      }
    }
  }
  float bq2[2][4];
  if (w >= 2){
#pragma unroll
    for (int j = 0; j < 2; j++)
#pragma unroll
      for (int r = 0; r < 4; r++)
        bq2[j][r] = A_.bq[((w-2)*2 + j)*16 + quad*4 + r];
  }
  float vv[16];
#pragma unroll
  for (int jj = 0; jj < 16; jj++) vv[jj] = A_.v[quad*16 + jj];
  const float bvv = A_.bv[0];
  const int slot = m*2 + (w - 2);   // valid for w>=2: 0..63
  const int ab = slot & 15, wr = (slot >> 4) & 3;

  // ----- init zeroing (committed RMWs), w0/w1 arrive c4 (64 init arrivals) --
  if (w == 1){
    f32x4 z = {0,0,0,0};
    usink += astore_bf4r(&h0b[m16*NH + d0 + quad*4], z);
    usink += astore_bf4r(&h1b[m16*NH + d0 + quad*4], z);
  }
  if (w == 0){
    if (lane < 16){
      usink += azero8r((u64*)ctxg + m*16 + lane);
      usink += azero8r((u64*)ctxg + 512 + m*16 + lane);
    }
    if (lane == 16 && m < 8){
      usink += azero8r((u64*)deng + m);
      usink += azero8r((u64*)deng + 8 + m);
    }
  }
  int myidx = 0, imax = 0;
#pragma unroll 1
  for (int b = 0; b < GB; b++){
    int L = A_.len[b0 + b];
    int ix = L - 2; ix = ix < 0 ? 0 : (ix > NT-1 ? NT-1 : ix);
    if (b == m16) myidx = ix;
    imax = imax > ix ? imax : ix;
  }
  if (w < 2){
    WAIT_VM0();
    arrive(c4);
  }
  __syncthreads();   // wih1s visible

  f32x4 gh0c[3];     // carried Whh0.h0 + bhh0 (h0 starts at 0 -> bias)
  if (w == 0){
#pragma unroll
    for (int gate = 0; gate < 3; gate++)
#pragma unroll
      for (int r = 0; r < 4; r++) gh0c[gate][r] = bh[gate][r];
  }
  f32x4 h0p = {0,0,0,0}, h1p = {0,0,0,0};
  f32x4 gh1[3];

#pragma unroll 1
  for (int i = 0; i <= imax; i++){
    // ---- S0: wait h1(i-1) published, stage it ----
    pollge(c4, 64 + 32*i);
    stage_h(h1b, h1s, tid);
    __syncthreads();

    // ---- S1: q slices (w2: 0,1 ; w3: 2,3) ----
    if (w >= 2){
#pragma unroll
      for (int j = 0; j < 2; j++){
        const int s = (w-2)*2 + j;
        f32x4 qa = {0,0,0,0};
#pragma unroll
        for (int kc = 0; kc < 16; kc++){
          bf16x8 af = *(const bf16x8*)&A_.wqblob[((s*16 + kc)*64 + lane)*8];
          bf16x8 bf = *(const bf16x8*)&h1s[kc][lane][0];
          qa = MFMA(af, bf, qa);
        }
#pragma unroll
        for (int r = 0; r < 4; r++)
          qs[m16][s*16 + quad*4 + r] = qa[r] + bq2[j][r];
      }
    }
    __syncthreads();   // qs ready

    if (w == 1){
      // gh1 = Whh1.h1 + bhh1 (overlaps attention)
#pragma unroll
      for (int gate = 0; gate < 3; gate++){ f32x4 z={0,0,0,0}; gh1[gate]=z; }
#pragma unroll
      for (int kc = 0; kc < 16; kc++){
        bf16x8 bf = *(const bf16x8*)&h1s[kc][lane][0];
#pragma unroll
        for (int gate = 0; gate < 3; gate++)
          gh1[gate] = MFMA(whhf[gate][kc], bf, gh1[gate]);
      }
#pragma unroll
      for (int gate = 0; gate < 3; gate++)
#pragma unroll
        for (int r = 0; r < 4; r++) gh1[gate][r] += bh[gate][r];
    } else if (w >= 2){
      // ---- S2: attention for batch ab, chunk phase wr (stride 4) ----
      float qv[16];
#pragma unroll
      for (int jq = 0; jq < 4; jq++){
        f32x4 t = *(const f32x4*)&qs[ab][quad*16 + jq*4];
        qv[jq*4+0]=t[0]; qv[jq*4+1]=t[1]; qv[jq*4+2]=t[2]; qv[jq*4+3]=t[3];
      }
      float ctxp[16];
#pragma unroll
      for (int jj = 0; jj < 16; jj++) ctxp[jj] = 0.f;
      float denp = 0.f;
      const us* tpb = A_.tp + (long)(b0 + ab) * NT * NA;
#pragma unroll 1
      for (int c = wr; c*16 <= i; c += 4){
        const int t = c*16 + m16;
        const us* tpp = tpb + (long)t*NA + quad*16;
        u16x8 ta = *(const u16x8*)tpp;
        u16x8 tb = *(const u16x8*)(tpp + 8);
        float tpf[16];
#pragma unroll
        for (int jj = 0; jj < 8; jj++){ tpf[jj] = bf2f(ta[jj]); tpf[8+jj] = bf2f(tb[jj]); }
        float sp = 0.f;
#pragma unroll
        for (int jj = 0; jj < 16; jj++){
          float x = tpf[jj] + qv[jj];
          sp = fmaf(ftanh(x), vv[jj], sp);
        }
        sp += __shfl_xor(sp, 16);
        sp += __shfl_xor(sp, 32);
        float e = __expf(sp + bvv);
        e = (t <= i) ? e : 0.f;
        denp += e;
#pragma unroll
        for (int jj = 0; jj < 16; jj++) ctxp[jj] = fmaf(e, tpf[jj], ctxp[jj]);
      }
#pragma unroll
      for (int off = 1; off < 64; off <<= 1) denp += __shfl_xor(denp, off);
      denp *= 0.25f;
#pragma unroll
      for (int st = 0; st < 4; st++){
        const int bit = 1 << st;
        const bool up = (lane >> st) & 1;
        const int n2 = (16 >> st) >> 1;
#pragma unroll
        for (int j2 = 0; j2 < 8; j2++){
          if (j2 < n2){
            float keep = up ? ctxp[2*j2+1] : ctxp[2*j2];
            float send = up ? ctxp[2*j2]   : ctxp[2*j2+1];
            float got = __shfl_xor(send, bit);
            ctxp[j2] = keep + got;
          }
        }
      }
      const int par = i & 1;
      fsink += afaddr(&ctxg[par*GB*NA + ab*NA + lane], ctxp[0]);
      if (lane == 0) fsink += afaddr(&deng[par*GB + ab], denp);
      WAIT_VM0();
      arrive(c2);
    } else {
      // ---- w0 / S3: wait ctx, gi0, combine, publish h0 ----
      pollge(c2, 64*(i+1));
      const int par = i & 1;
      const float rdn = 1.0f / aload_f(&deng[par*GB + m16]);
      f32x4 gi0[3] = {{0,0,0,0},{0,0,0,0},{0,0,0,0}};
#pragma unroll
      for (int kc = 0; kc < 2; kc++){
        const float* cp = &ctxg[par*GB*NA + m16*NA + kc*32 + quad*8];
        f32x4 c0, c1;
        fpair p0 = aload_f2(cp+0); c0[0]=p0.x; c0[1]=p0.y;
        fpair p1 = aload_f2(cp+2); c0[2]=p1.x; c0[3]=p1.y;
        fpair p2 = aload_f2(cp+4); c1[0]=p2.x; c1[1]=p2.y;
        fpair p3 = aload_f2(cp+6); c1[2]=p3.x; c1[3]=p3.y;
#pragma unroll
        for (int r = 0; r < 4; r++){ c0[r] *= rdn; c1[r] *= rdn; }
        bf16x8 bfr = packbf2(c0, c1);
#pragma unroll
        for (int gate = 0; gate < 3; gate++)
          gi0[gate] = MFMA(wih0f[gate][kc], bfr, gi0[gate]);
      }
      f32x4 hn;
#pragma unroll
      for (int r = 0; r < 4; r++){
        float rr = fsig(gi0[0][r] + bi[0][r] + gh0c[0][r]);
        float zz = fsig(gi0[1][r] + bi[1][r] + gh0c[1][r]);
        float nn = ftanh(gi0[2][r] + bi[2][r] + rr*gh0c[2][r]);
        hn[r] = (1.f - zz)*nn + zz*h0p[r];
      }
      h0p = hn;
      usink += astore_bf4r(&h0b[m16*NH + d0 + quad*4], hn);
      // clear next-parity ctx/den (last read two steps ago -> safe)
      const int np = (i + 1) & 1;
      if (lane < 16) usink += azero8r((u64*)ctxg + np*512 + m*16 + lane);
      if (lane == 16 && m < 8) usink += azero8r((u64*)deng + np*8 + m);
      WAIT_VM0();
      arrive(c3);
    }

    // ---- S4: wait all h0 published, stage it ----
    pollge(c3, 32*(i+1));
    stage_h(h0b, h0s, tid);
    __syncthreads();

    // ---- S5 ----
    if (w == 1){
      f32x4 gi1[3] = {{0,0,0,0},{0,0,0,0},{0,0,0,0}};
#pragma unroll
      for (int kc = 0; kc < 16; kc++){
        bf16x8 bf = *(const bf16x8*)&h0s[kc][lane][0];
#pragma unroll
        for (int gate = 0; gate < 3; gate++){
          bf16x8 af = *(const bf16x8*)&wih1s[gate*16 + kc][lane][0];
          gi1[gate] = MFMA(af, bf, gi1[gate]);
        }
      }
      f32x4 hn;
#pragma unroll
      for (int r = 0; r < 4; r++){
        float rr = fsig(gi1[0][r] + bi[0][r] + gh1[0][r]);
        float zz = fsig(gi1[1][r] + bi[1][r] + gh1[1][r]);
        float nn = ftanh(gi1[2][r] + bi[2][r] + rr*gh1[2][r]);
        hn[r] = (1.f - zz)*nn + zz*h1p[r];
      }
      h1p = hn;
      usink += astore_bf4r(&h1b[m16*NH + d0 + quad*4], hn);
      if (i == myidx)
        *(f32x4*)&A_.out[(long)(b0 + m16)*NH + d0 + quad*4] = hn;
      WAIT_VM0();
      arrive(c4);
    } else if (w == 0){
      // next step's gh0 = Whh0.h0 + bhh0 (overlaps w1's work)
      f32x4 a0={0,0,0,0}, a1={0,0,0,0}, a2={0,0,0,0};
#pragma unroll
      for (int kc = 0; kc < 16; kc++){
        bf16x8 bf = *(const bf16x8*)&h0s[kc][lane][0];
        a0 = MFMA(whhf[0][kc], bf, a0);
        a1 = MFMA(whhf[1][kc], bf, a1);
        a2 = MFMA(whhf[2][kc], bf, a2);
      }
#pragma unroll
      for (int r = 0; r < 4; r++){
        gh0c[0][r] = a0[r] + bh[0][r];
        gh0c[1][r] = a1[r] + bh[1][r];
        gh0c[2][r] = a2[r] + bh[2][r];
      }
    }
  }

  // keep RMW returns alive (condition never true)
  u64 total = usink + (u64)__builtin_bit_cast(unsigned, fsink);
  if (total == 0x9e3779b97f4a7c15ull && A_.len[0] == -12345)
    A_.ctrl[56 + g] = (int)total;
}

// ---------------------------------------------------------------------------
extern "C" void kernel_launch(void* const* d_in, const int* in_sizes, int n_in,
                              void* d_out, int out_size, void* d_ws, size_t ws_size,
                              hipStream_t stream)
{
  (void)in_sizes; (void)n_in; (void)out_size; (void)ws_size;
  char* ws = (char*)d_ws;
  us* tp  = (us*)ws;                                   // 8 MB
  us* h0b = (us*)(ws + 8388608);                       // 128 KB
  us* h1b = h0b + NB*NH;                               // 128 KB
  float* ctxg = (float*)(h1b + NB*NH);                 // [8][2][16][64] = 64 KB
  float* deng = ctxg + NG*2*GB*NA;                     // [8][2][16] = 1 KB -> pad 4KB
  int* ctrl   = (int*)((char*)deng + 4096);            // 2 KB
  us* wqblob  = (us*)((char*)ctrl + 2048);             // 64 KB

  (void)hipMemsetAsync(ctrl, 0, 2048, stream);

  k_tp<<<dim3(256), dim3(256), 0, stream>>>(
      (const int*)d_in[0], (const float*)d_in[2], (const float*)d_in[3],
      (const float*)d_in[4], tp);
  k_pack<<<dim3(1), dim3(256), 0, stream>>>((const float*)d_in[5], wqblob);

  KArgs ka;
  ka.len  = (const int*)d_in[1];
  ka.bq   = (const float*)d_in[6];
  ka.v    = (const float*)d_in[7];  ka.bv   = (const float*)d_in[8];
  ka.Wih0 = (const float*)d_in[9];  ka.Whh0 = (const float*)d_in[10];
  ka.bih0 = (const float*)d_in[11]; ka.bhh0 = (const float*)d_in[12];
  ka.Wih1 = (const float*)d_in[13]; ka.Whh1 = (const float*)d_in[14];
  ka.bih1 = (const float*)d_in[15]; ka.bhh1 = (const float*)d_in[16];
  ka.tp = tp; ka.wqblob = wqblob; ka.h0b = h0b; ka.h1b = h1b;
  ka.ctxg = ctxg; ka.deng = deng; ka.ctrl = ctrl; ka.out = (float*)d_out;

  k_main<<<dim3(256), dim3(256), 0, stream>>>(ka);
}